// Round 7
// baseline (412.451 us; speedup 1.0000x reference)
//
#include <hip/hip_runtime.h>

#define TT 512

typedef _Float16 half8 __attribute__((ext_vector_type(8)));
typedef __attribute__((ext_vector_type(4))) float floatx4;

__device__ __forceinline__ float fast_tanh(float z) {
    const float e = __expf(2.f * z);
    return 1.f - __fdividef(2.f, e + 1.f);
}
__device__ __forceinline__ float f4e(const float4& v, int r) {
    return (r == 0) ? v.x : (r == 1) ? v.y : (r == 2) ? v.z : v.w;
}
__device__ __forceinline__ unsigned pk16(float a, float b) {
    const unsigned ua = __builtin_bit_cast(unsigned short, (_Float16)a);
    const unsigned ub = __builtin_bit_cast(unsigned short, (_Float16)b);
    return ua | (ub << 16);
}

// R7: R10 dataflow with the per-interval s_barrier replaced by point-to-point
// LDS flag sync (per-wave interval counters). Waves proceed as soon as THEIR
// inputs exist -> no 8-wave convoy, intervals overlap across waves.
// Ordering: per-CU LDS FIFO is in-order (validated R6-R12): producer writes
// slice THEN counter (asm-clobber-ordered); consumer polls counter, then reads
// data -> data guaranteed committed. Rings: h0 depth 8, h1 depth 4.
// Skew bounds: mutual lag-1 polls bound L0<->L0 and L1<->L1 skew to 1; the
// producer-side check (all L1 >= i-6) stops L0 overwriting h0 ring entries L1
// still needs (L1 steady-state lag is 2 -> slack 4, rarely blocks).
// Arithmetic bit-identical to R10 (absmax 4.882812e-4).
__global__ void __launch_bounds__(512, 1)
rnn2_flag(const float* __restrict__ x,
          const float* __restrict__ W_ih0, const float* __restrict__ W_hh0,
          const float* __restrict__ b_ih0, const float* __restrict__ b_hh0,
          const float* __restrict__ W_ih1, const float* __restrict__ W_hh1,
          const float* __restrict__ b_ih1, const float* __restrict__ b_hh1,
          const float* __restrict__ W_fc, const float* __restrict__ b_fc,
          float* __restrict__ out)
{
    __shared__ short h0f[8][1024];          // h0 ring: entry t&7 holds h0(t)
    __shared__ short h1f[4][1024];          // h1 ring: entry t&3 holds h1(t)
    __shared__ alignas(16) int cnt[8];      // per-wave last completed interval
    __shared__ float red[4][16];

    const int tid = threadIdx.x;
    const int lane = tid & 63;
    const int w = tid >> 6;          // 0..7
    const int wq = w & 3;            // M-slice within the layer group
    const bool isL0 = (w < 4);
    const int n = lane & 15;
    const int q = lane >> 4;
    const int b0 = blockIdx.x * 16;

    // init: h0(-1)=0 (ring entry 7), h1(-1)=0 (ring entry 3), counters=-1
    if (tid < 256)      ((int*)&h0f[7][0])[tid] = 0;
    else if (tid < 512) ((int*)&h1f[3][0])[tid - 256] = 0;
    if (tid < 8) cnt[tid] = -1;

    const int mrow = 16 * wq + n;
    const int m4 = 16 * wq + 4 * q;
    const int rbase = 128 * q + 8 * n;
    const int wbase = (2 * wq + (q >> 1)) * 128 + 8 * n + 4 * (q & 1);

    // ---- weight fragments, single fp16 RTNE (exactly as R10) ----
    half8 wA[2], wB[2];  // L0: A=W_hh0 ; L1: A=W_ih1, B=W_hh1
    auto mkfrag = [&](const float* p, half8& hi) {
#pragma unroll
        for (int j = 0; j < 8; ++j) hi[j] = (_Float16)p[j];
    };
    float4 wih0v = {0, 0, 0, 0}, bv0 = {0, 0, 0, 0}, bv1 = {0, 0, 0, 0}, wfcv = {0, 0, 0, 0};
    if (isL0) {
#pragma unroll
        for (int k = 0; k < 2; ++k) mkfrag(W_hh0 + mrow * 64 + 32 * k + 8 * q, wA[k]);
        wih0v = *(const float4*)(W_ih0 + m4);
        bv0 = *(const float4*)(b_ih0 + m4);
        { float4 t = *(const float4*)(b_hh0 + m4); bv0.x += t.x; bv0.y += t.y; bv0.z += t.z; bv0.w += t.w; }
    } else {
#pragma unroll
        for (int k = 0; k < 2; ++k) {
            mkfrag(W_ih1 + mrow * 64 + 32 * k + 8 * q, wA[k]);
            mkfrag(W_hh1 + mrow * 64 + 32 * k + 8 * q, wB[k]);
        }
        bv1 = *(const float4*)(b_ih1 + m4);
        { float4 t = *(const float4*)(b_hh1 + m4); bv1.x += t.x; bv1.y += t.y; bv1.z += t.z; bv1.w += t.w; }
        wfcv = *(const float4*)(W_fc + m4);
    }

    const float* xp = x + (long)(b0 + n) * TT;
    const floatx4 zero4 = {0.f, 0.f, 0.f, 0.f};

    __syncthreads();   // zero-init + counters visible to all waves (once)

    // ---- sync primitives ----
    auto publish = [&](int i) {
        __asm__ volatile("" ::: "memory");
        if (lane == 0) cnt[w] = i;
        __asm__ volatile("" ::: "memory");
    };
    // L0 wave at interval i: L0 peers >= i-1 (read h0(i-1)); L1 >= i-6
    // (flow control: about to overwrite ring entry i&7 = h0(i-8)).
    auto pollL0 = [&](int i) {
        const int t1 = i - 1, t2 = i - 6;
        for (;;) {
            __asm__ volatile("" ::: "memory");
            const int c0 = cnt[0], c1 = cnt[1], c2 = cnt[2], c3 = cnt[3];
            const int c4 = cnt[4], c5 = cnt[5], c6 = cnt[6], c7 = cnt[7];
            if (c0 >= t1 && c1 >= t1 && c2 >= t1 && c3 >= t1 &&
                c4 >= t2 && c5 >= t2 && c6 >= t2 && c7 >= t2) break;
        }
        __asm__ volatile("" ::: "memory");
    };
    // L1 wave at interval i: L0 >= min(i-1,511) (h0(i-1) prefetch);
    // L1 peers >= i-1 (read h1(i-3), written at peer interval i-1).
    auto pollL1 = [&](int i) {
        const int t0 = (i - 1 > 511) ? 511 : (i - 1);
        const int t1 = i - 1;
        for (;;) {
            __asm__ volatile("" ::: "memory");
            const int c0 = cnt[0], c1 = cnt[1], c2 = cnt[2], c3 = cnt[3];
            const int c4 = cnt[4], c5 = cnt[5], c6 = cnt[6], c7 = cnt[7];
            if (c0 >= t0 && c1 >= t0 && c2 >= t0 && c3 >= t0 &&
                c4 >= t1 && c5 >= t1 && c6 >= t1 && c7 >= t1) break;
        }
        __asm__ volatile("" ::: "memory");
    };

    auto epi_write = [&](const floatx4& A, const floatx4& B, short* pf) {
        float h[4];
#pragma unroll
        for (int r = 0; r < 4; ++r) h[r] = fast_tanh(A[r] + B[r]);
        uint2 u;
        u.x = pk16(h[0], h[1]);
        u.y = pk16(h[2], h[3]);
        *(uint2*)&pf[wbase] = u;
    };

    if (isL0) {
        // ---- interval 0: h0(0) = tanh(x*W_ih0 + b), scalar (h(-1)=0) ----
        const float xv0 = xp[0];
        float h[4];
#pragma unroll
        for (int r = 0; r < 4; ++r)
            h[r] = fast_tanh(__builtin_fmaf(xv0, f4e(wih0v, r), f4e(bv0, r)));
        uint2 u; u.x = pk16(h[0], h[1]); u.y = pk16(h[2], h[3]);
        *(uint2*)&h0f[0][wbase] = u;
        publish(0);
        float xv = xp[1], xnext = xp[2];
        // ---- intervals 1..511 ----
        for (int i = 1; i < 512; ++i) {
            pollL0(i);
            const short* rp = &h0f[(i - 1) & 7][0];
            half8 b0v = *(const half8*)&rp[rbase];
            half8 b1v = *(const half8*)&rp[rbase + 512];
            floatx4 aA = {__builtin_fmaf(xv, wih0v.x, bv0.x), __builtin_fmaf(xv, wih0v.y, bv0.y),
                          __builtin_fmaf(xv, wih0v.z, bv0.z), __builtin_fmaf(xv, wih0v.w, bv0.w)};
            floatx4 aB = zero4;
            aA = __builtin_amdgcn_mfma_f32_16x16x32_f16(wA[0], b0v, aA, 0, 0, 0);
            aB = __builtin_amdgcn_mfma_f32_16x16x32_f16(wA[1], b1v, aB, 0, 0, 0);
            xv = xnext; xnext = xp[(i + 2) & (TT - 1)];
            epi_write(aA, aB, &h0f[i & 7][0]);
            publish(i);
        }
    } else {
        half8 bp[2];
        publish(0);                       // interval 0: nothing to do
        // ---- interval 1: prefetch h0(0) ----
        pollL1(1);
        bp[0] = *(const half8*)&h0f[0][rbase];
        bp[1] = *(const half8*)&h0f[0][rbase + 512];
        publish(1);
        // ---- intervals 2..512: compute h1(i-2), prefetch h0(i-1) ----
        for (int i = 2; i <= 512; ++i) {
            pollL1(i);
            const short* rc = &h1f[(i - 3) & 3][0];
            const short* rb = &h0f[(i - 1) & 7][0];
            half8 c0 = *(const half8*)&rc[rbase];
            half8 c1 = *(const half8*)&rc[rbase + 512];
            half8 nb0 = *(const half8*)&rb[rbase];
            half8 nb1 = *(const half8*)&rb[rbase + 512];
            floatx4 aA = {bv1.x, bv1.y, bv1.z, bv1.w};
            floatx4 aB = zero4;
            aA = __builtin_amdgcn_mfma_f32_16x16x32_f16(wA[0], bp[0], aA, 0, 0, 0);
            aA = __builtin_amdgcn_mfma_f32_16x16x32_f16(wA[1], bp[1], aA, 0, 0, 0);
            aB = __builtin_amdgcn_mfma_f32_16x16x32_f16(wB[0], c0, aB, 0, 0, 0);
            aB = __builtin_amdgcn_mfma_f32_16x16x32_f16(wB[1], c1, aB, 0, 0, 0);
            epi_write(aA, aB, &h1f[(i - 2) & 3][0]);
            bp[0] = nb0; bp[1] = nb1;
            publish(i);
        }
        // ---- interval 513: h1(511) in regs + FC dot ----
        pollL1(513);
        {
            const short* rc = &h1f[2][0];   // h1(510) = entry (513-3)&3
            half8 c0 = *(const half8*)&rc[rbase];
            half8 c1 = *(const half8*)&rc[rbase + 512];
            floatx4 aA = {bv1.x, bv1.y, bv1.z, bv1.w};
            floatx4 aB = zero4;
            aA = __builtin_amdgcn_mfma_f32_16x16x32_f16(wA[0], bp[0], aA, 0, 0, 0);  // h0(511)
            aA = __builtin_amdgcn_mfma_f32_16x16x32_f16(wA[1], bp[1], aA, 0, 0, 0);
            aB = __builtin_amdgcn_mfma_f32_16x16x32_f16(wB[0], c0, aB, 0, 0, 0);
            aB = __builtin_amdgcn_mfma_f32_16x16x32_f16(wB[1], c1, aB, 0, 0, 0);
            float p = 0.f;
#pragma unroll
            for (int r = 0; r < 4; ++r) {
                const float h = fast_tanh(aA[r] + aB[r]);
                p = __builtin_fmaf(h, f4e(wfcv, r), p);
            }
            p += __shfl_xor(p, 16, 64);
            p += __shfl_xor(p, 32, 64);
            if (lane < 16) red[wq][lane] = p;
        }
    }
    __syncthreads();
    if (w == 4 && lane < 16)
        out[b0 + lane] = red[0][lane] + red[1][lane] + red[2][lane] + red[3][lane] + b_fc[0];
}

extern "C" void kernel_launch(void* const* d_in, const int* in_sizes, int n_in,
                              void* d_out, int out_size, void* d_ws, size_t ws_size,
                              hipStream_t stream) {
    const float* x     = (const float*)d_in[0];
    const float* W_ih0 = (const float*)d_in[1];
    const float* W_hh0 = (const float*)d_in[2];
    const float* b_ih0 = (const float*)d_in[3];
    const float* b_hh0 = (const float*)d_in[4];
    const float* W_ih1 = (const float*)d_in[5];
    const float* W_hh1 = (const float*)d_in[6];
    const float* b_ih1 = (const float*)d_in[7];
    const float* b_hh1 = (const float*)d_in[8];
    const float* W_fc  = (const float*)d_in[9];
    const float* b_fc  = (const float*)d_in[10];
    float* out = (float*)d_out;

    rnn2_flag<<<128, 512, 0, stream>>>(x, W_ih0, W_hh0, b_ih0, b_hh0,
                                       W_ih1, W_hh1, b_ih1, b_hh1,
                                       W_fc, b_fc, out);
}

// Round 8
// 277.062 us; speedup vs baseline: 1.4887x; 1.4887x over previous
//
#include <hip/hip_runtime.h>

#define TT 512

typedef _Float16 half8 __attribute__((ext_vector_type(8)));
typedef __attribute__((ext_vector_type(4))) float floatx4;

// raw workgroup barrier (no vmcnt/lgkmcnt drain); LDS FIFO is in-order per CU,
// validated R6-R12 (reads issued pre-barrier stay bit-exact vs post-barrier
// overwrites across 512 steps).
#define BAR() do { __asm__ volatile("" ::: "memory"); \
                   __builtin_amdgcn_s_barrier();      \
                   __asm__ volatile("" ::: "memory"); } while (0)

__device__ __forceinline__ float fast_tanh(float z) {
    const float e = __expf(2.f * z);
    return 1.f - __fdividef(2.f, e + 1.f);
}
__device__ __forceinline__ float f4e(const float4& v, int r) {
    return (r == 0) ? v.x : (r == 1) ? v.y : (r == 2) ? v.z : v.w;
}
__device__ __forceinline__ unsigned pk16(float a, float b) {
    const unsigned ua = __builtin_bit_cast(unsigned short, (_Float16)a);
    const unsigned ub = __builtin_bit_cast(unsigned short, (_Float16)b);
    return ua | (ub << 16);
}

// R8 = R10 champion with the L1 h0-prefetch reads moved OUT of the
// post-barrier LDS burst. At barrier release all 8 waves previously issued
// 24 ds_read_b128 back-to-back (~190 cy of serialized LDS port time on the
// critical path). The 8 nb-prefetch reads (h0(i-1), consumed next interval)
// now issue after epi_write, when the port is idle. h0f[rbn] is stable all
// interval (L0 writes the other parity); completion before next-interval
// overwrite is the validated pre-barrier-read property. Arithmetic is
// bit-identical to R10 (absmax 4.882812e-4).
__global__ void __launch_bounds__(512, 1)
rnn2_burst(const float* __restrict__ x,
           const float* __restrict__ W_ih0, const float* __restrict__ W_hh0,
           const float* __restrict__ b_ih0, const float* __restrict__ b_hh0,
           const float* __restrict__ W_ih1, const float* __restrict__ W_hh1,
           const float* __restrict__ b_ih1, const float* __restrict__ b_hh1,
           const float* __restrict__ W_fc, const float* __restrict__ b_fc,
           float* __restrict__ out)
{
    __shared__ short h0f[2][1024];  // [parity][chunk*512 + 128q + 8n + j], fp16
    __shared__ short h1f[2][1024];
    __shared__ float red[4][16];

    const int tid = threadIdx.x;
    const int lane = tid & 63;
    const int w = tid >> 6;          // 0..7
    const int wq = w & 3;            // M-slice within the layer group
    const bool isL0 = (w < 4);
    const int n = lane & 15;
    const int q = lane >> 4;
    const int b0 = blockIdx.x * 16;

    // h1(-1) = 0 at parity 1 (read as c by L1 at interval 2)
    ((int*)&h1f[1][0])[tid] = 0;

    const int mrow = 16 * wq + n;
    const int m4 = 16 * wq + 4 * q;
    const int rbase = 128 * q + 8 * n;
    const int wbase = (2 * wq + (q >> 1)) * 128 + 8 * n + 4 * (q & 1);

    // ---- weight fragments, single fp16 RTNE (as R10) ----
    half8 wA[2], wB[2];  // L0: A=W_hh0 ; L1: A=W_ih1, B=W_hh1
    auto mkfrag = [&](const float* p, half8& hi) {
#pragma unroll
        for (int j = 0; j < 8; ++j) hi[j] = (_Float16)p[j];
    };
    float4 wih0v = {0, 0, 0, 0}, bv0 = {0, 0, 0, 0}, bv1 = {0, 0, 0, 0}, wfcv = {0, 0, 0, 0};
    if (isL0) {
#pragma unroll
        for (int k = 0; k < 2; ++k) mkfrag(W_hh0 + mrow * 64 + 32 * k + 8 * q, wA[k]);
        wih0v = *(const float4*)(W_ih0 + m4);
        bv0 = *(const float4*)(b_ih0 + m4);
        { float4 t = *(const float4*)(b_hh0 + m4); bv0.x += t.x; bv0.y += t.y; bv0.z += t.z; bv0.w += t.w; }
    } else {
#pragma unroll
        for (int k = 0; k < 2; ++k) {
            mkfrag(W_ih1 + mrow * 64 + 32 * k + 8 * q, wA[k]);
            mkfrag(W_hh1 + mrow * 64 + 32 * k + 8 * q, wB[k]);
        }
        bv1 = *(const float4*)(b_ih1 + m4);
        { float4 t = *(const float4*)(b_hh1 + m4); bv1.x += t.x; bv1.y += t.y; bv1.z += t.z; bv1.w += t.w; }
        wfcv = *(const float4*)(W_fc + m4);
    }

    const float* xp = x + (long)(b0 + n) * TT;
    const floatx4 zero4 = {0.f, 0.f, 0.f, 0.f};

    auto epi_write = [&](const floatx4& A, const floatx4& B, short* pf) {
        float h[4];
#pragma unroll
        for (int r = 0; r < 4; ++r) h[r] = fast_tanh(A[r] + B[r]);
        uint2 u;
        u.x = pk16(h[0], h[1]);
        u.y = pk16(h[2], h[3]);
        *(uint2*)&pf[wbase] = u;
    };

    // L0 interval: read h0[rp] (exposed, issued first), compute h0, write h0[wp]
    auto stepL0 = [&](int rp, int wp, float xvv) {
        half8 b0v = *(const half8*)&h0f[rp][rbase];
        half8 b1v = *(const half8*)&h0f[rp][rbase + 512];
        floatx4 aA = {__builtin_fmaf(xvv, wih0v.x, bv0.x), __builtin_fmaf(xvv, wih0v.y, bv0.y),
                      __builtin_fmaf(xvv, wih0v.z, bv0.z), __builtin_fmaf(xvv, wih0v.w, bv0.w)};
        floatx4 aB = zero4;
        aA = __builtin_amdgcn_mfma_f32_16x16x32_f16(wA[0], b0v, aA, 0, 0, 0);
        aB = __builtin_amdgcn_mfma_f32_16x16x32_f16(wA[1], b1v, aB, 0, 0, 0);
        epi_write(aA, aB, &h0f[wp][0]);
    };

    // L1 interval: own-recurrence read (c) first, compute on PREFETCHED bp
    // (no wait), write; THEN prefetch next h0 (bn) late - off the release burst.
    auto stepL1 = [&](int rc, int rbn, int wp, half8* bp) {
        half8 c0 = *(const half8*)&h1f[rc][rbase];
        half8 c1 = *(const half8*)&h1f[rc][rbase + 512];
        floatx4 aA = {bv1.x, bv1.y, bv1.z, bv1.w};
        floatx4 aB = zero4;
        aA = __builtin_amdgcn_mfma_f32_16x16x32_f16(wA[0], bp[0], aA, 0, 0, 0);
        aA = __builtin_amdgcn_mfma_f32_16x16x32_f16(wA[1], bp[1], aA, 0, 0, 0);
        aB = __builtin_amdgcn_mfma_f32_16x16x32_f16(wB[0], c0, aB, 0, 0, 0);
        aB = __builtin_amdgcn_mfma_f32_16x16x32_f16(wB[1], c1, aB, 0, 0, 0);
        epi_write(aA, aB, &h1f[wp][0]);
        // late prefetch: LDS port is idle here; h0f[rbn] is stable this
        // interval and the read completes before the next-interval overwrite
        // (validated in-order-FIFO / pre-barrier-read property).
        bp[0] = *(const half8*)&h0f[rbn][rbase];
        bp[1] = *(const half8*)&h0f[rbn][rbase + 512];
    };

    // ---- interval 0: L0 writes h0(0) -> parity 0 ----
    float xv = 0.f, xnext = 0.f;
    if (isL0) {
        const float xv0 = xp[0];
        float h[4];
#pragma unroll
        for (int r = 0; r < 4; ++r)
            h[r] = fast_tanh(__builtin_fmaf(xv0, f4e(wih0v, r), f4e(bv0, r)));
        uint2 u; u.x = pk16(h[0], h[1]); u.y = pk16(h[2], h[3]);
        *(uint2*)&h0f[0][wbase] = u;
        xv = xp[1];
        xnext = xp[2];
    }
    BAR();

    // ---- interval 1: L0 h0(1); L1 prefetches h0(0) ----
    half8 bp[2];
    if (isL0) {
        stepL0(0, 1, xv);
        xv = xnext; xnext = xp[3];
    } else {
        bp[0] = *(const half8*)&h0f[0][rbase];
        bp[1] = *(const half8*)&h0f[0][rbase + 512];
    }
    BAR();

    // ---- main loop: intervals i = 2..511 (pairs) ----
    // interval i: L0 computes h0(i); L1 computes h1(i-2), prefetches h0(i-1)
    for (int i = 2; i < 511; i += 2) {
        // P = 0
        if (isL0) {
            stepL0(1, 0, xv);
            xv = xnext; xnext = xp[(i + 2) & (TT - 1)];
        } else {
            stepL1(1, 1, 0, bp);
        }
        BAR();
        // P = 1
        if (isL0) {
            stepL0(0, 1, xv);
            xv = xnext; xnext = xp[(i + 3) & (TT - 1)];
        } else {
            stepL1(0, 0, 1, bp);
        }
        BAR();
    }

    // ---- tail interval 512: L1 computes h1(510), prefetches h0(511) ----
    if (!isL0) stepL1(1, 1, 0, bp);
    BAR();

    // ---- tail interval 513: L1 computes h1(511) in regs + FC dot ----
    float p = 0.f;
    if (!isL0) {
        half8 c0 = *(const half8*)&h1f[0][rbase];        // h1(510), parity 0
        half8 c1 = *(const half8*)&h1f[0][rbase + 512];
        floatx4 aA = {bv1.x, bv1.y, bv1.z, bv1.w};
        floatx4 aB = zero4;
        aA = __builtin_amdgcn_mfma_f32_16x16x32_f16(wA[0], bp[0], aA, 0, 0, 0);  // h0(511)
        aA = __builtin_amdgcn_mfma_f32_16x16x32_f16(wA[1], bp[1], aA, 0, 0, 0);
        aB = __builtin_amdgcn_mfma_f32_16x16x32_f16(wB[0], c0, aB, 0, 0, 0);
        aB = __builtin_amdgcn_mfma_f32_16x16x32_f16(wB[1], c1, aB, 0, 0, 0);
#pragma unroll
        for (int r = 0; r < 4; ++r) {
            const float h = fast_tanh(aA[r] + aB[r]);
            p = __builtin_fmaf(h, f4e(wfcv, r), p);
        }
        p += __shfl_xor(p, 16, 64);
        p += __shfl_xor(p, 32, 64);
        if (lane < 16) red[wq][lane] = p;
    }
    __syncthreads();
    if (w == 4 && lane < 16)
        out[b0 + lane] = red[0][lane] + red[1][lane] + red[2][lane] + red[3][lane] + b_fc[0];
}

extern "C" void kernel_launch(void* const* d_in, const int* in_sizes, int n_in,
                              void* d_out, int out_size, void* d_ws, size_t ws_size,
                              hipStream_t stream) {
    const float* x     = (const float*)d_in[0];
    const float* W_ih0 = (const float*)d_in[1];
    const float* W_hh0 = (const float*)d_in[2];
    const float* b_ih0 = (const float*)d_in[3];
    const float* b_hh0 = (const float*)d_in[4];
    const float* W_ih1 = (const float*)d_in[5];
    const float* W_hh1 = (const float*)d_in[6];
    const float* b_ih1 = (const float*)d_in[7];
    const float* b_hh1 = (const float*)d_in[8];
    const float* W_fc  = (const float*)d_in[9];
    const float* b_fc  = (const float*)d_in[10];
    float* out = (float*)d_out;

    rnn2_burst<<<128, 512, 0, stream>>>(x, W_ih0, W_hh0, b_ih0, b_hh0,
                                        W_ih1, W_hh1, b_ih1, b_hh1,
                                        W_fc, b_fc, out);
}